// Round 1
// baseline (588.878 us; speedup 1.0000x reference)
//
#include <hip/hip_runtime.h>
#include <hip/hip_bf16.h>
#include <math.h>

// Problem constants (fixed instance)
#define NTOK 2048
#define DIM 512
#define NCEN 500
#define NHEAD 8
#define HD 64
#define KWIN 128
#define DEPTH 8

// ---------------- workspace layout (bytes) ----------------
// cenT  f64 [512][512]          @ 0        (2 MB)   (cols >=500 zero-filled)
// codes i32 [2048]              @ 2097152
// cnt   i32 [256]               @ 2105344
// offs  i32 [256]               @ 2106368
// bidx  i32 [2048]              @ 2107392
// routes i32 [2048][128]        @ 2115584  (1 MB)
// qkv   f32 [2048][1536]        @ 3164160  (12 MB)
// Obuf  f32 [2048][512]         @ 15747072 (4 MB)

// ------------------------------------------------------------------
// K1: centroids transposed, f64.  cenT[d][c] = mean_v p[c][v][d]
// grid 512 blocks (c), 256 threads (d strided). c>=500 -> 0.
__global__ __launch_bounds__(256) void centroids_k(const float* __restrict__ p,
                                                   double* __restrict__ cenT) {
    int c = blockIdx.x;
    for (int d = threadIdx.x; d < DIM; d += 256) {
        double s = 0.0;
        if (c < NCEN) {
            const float* pc = p + (size_t)c * 5 * DIM;
            s  = (double)pc[0 * DIM + d];
            s += (double)pc[1 * DIM + d];
            s += (double)pc[2 * DIM + d];
            s += (double)pc[3 * DIM + d];
            s += (double)pc[4 * DIM + d];
            s = s / 5.0;
        }
        cenT[(size_t)d * 512 + c] = s;
    }
}

// ------------------------------------------------------------------
// K2: cantor integer codes, all in f64.
// 256 blocks x 8 tokens, 256 threads.
__global__ __launch_bounds__(256) void codes_k(const float* __restrict__ x,
                                               const double* __restrict__ cenT,
                                               const float* __restrict__ gwp,
                                               int* __restrict__ codes) {
    __shared__ double xs[8][DIM];   // 32 KB
    __shared__ double red[256];
    __shared__ double nrm[8];
    int tid = threadIdx.x;
    int tok0 = blockIdx.x * 8;

    for (int t = 0; t < 8; ++t)
        for (int d = tid; d < DIM; d += 256)
            xs[t][d] = (double)x[(size_t)(tok0 + t) * DIM + d];
    __syncthreads();

    // norms: 8 groups of 32 lanes
    {
        int g = tid >> 5, l = tid & 31;
        double ss = 0.0;
        for (int d = l; d < DIM; d += 32) ss += xs[g][d] * xs[g][d];
        for (int m = 16; m; m >>= 1) ss += __shfl_xor(ss, m, 32);
        if (l == 0) nrm[g] = sqrt(ss) + 1e-12;
    }
    __syncthreads();
    for (int t = 0; t < 8; ++t)
        for (int d = tid; d < DIM; d += 256)
            xs[t][d] = xs[t][d] / nrm[t];
    __syncthreads();

    // sims: each thread owns centroids c0=tid, c1=tid+256
    int c0 = tid, c1 = tid + 256;
    double acc[8][2];
#pragma unroll
    for (int t = 0; t < 8; ++t) { acc[t][0] = 0.0; acc[t][1] = 0.0; }
    for (int d = 0; d < DIM; ++d) {
        double e0 = cenT[(size_t)d * 512 + c0];
        double e1 = cenT[(size_t)d * 512 + c1];
#pragma unroll
        for (int t = 0; t < 8; ++t) {
            double xv = xs[t][d];
            acc[t][0] += xv * e0;
            acc[t][1] += xv * e1;
        }
    }

    double gwv = 1.0 / (1.0 + exp(-(double)gwp[0]));
    const double delta = 1.0 / 2047.0;

    for (int t = 0; t < 8; ++t) {
        double m0 = acc[t][0];                 // c0 < 500 always (tid<=255)
        if (c1 < NCEN) m0 = fmax(m0, acc[t][1]);
        red[tid] = m0;
        __syncthreads();
        for (int s = 128; s > 0; s >>= 1) {
            if (tid < s) red[tid] = fmax(red[tid], red[tid + s]);
            __syncthreads();
        }
        if (tid == 0) {
            int n = tok0 + t;
            double gd = 1.0 - red[0];
            double pos = (n == NTOK - 1) ? 1.0 : (double)n * delta;
            double xc = pos * (1.0 - gwv) + gd * gwv;
            xc = fmin(fmax(xc, 1e-6), 1.0 - 1e-6);
            int code = 0;
#pragma unroll
            for (int l = 0; l < DEPTH; ++l) {
                double s3 = xc * 3.0;
                double dig = floor(s3);
                if (dig == 2.0) code |= 1 << (7 - l);
                xc = s3 - dig;
            }
            codes[n] = code;
        }
        __syncthreads();
    }
}

// ------------------------------------------------------------------
// K3: bucket tokens by code (counting sort, stable in index). 1 block.
__global__ __launch_bounds__(256) void bucket_k(const int* __restrict__ codes,
                                                int* __restrict__ cntg,
                                                int* __restrict__ offg,
                                                int* __restrict__ bidx) {
    __shared__ int cs[NTOK];
    __shared__ int cnts[256];
    __shared__ int offs[256];
    int v = threadIdx.x;
    for (int j = v; j < NTOK; j += 256) cs[j] = codes[j];
    __syncthreads();
    int cnt = 0;
    for (int j = 0; j < NTOK; ++j) cnt += (cs[j] == v) ? 1 : 0;
    cnts[v] = cnt;
    __syncthreads();
    if (v == 0) {
        int run = 0;
        for (int u = 0; u < 256; ++u) { offs[u] = run; run += cnts[u]; }
    }
    __syncthreads();
    int o = offs[v];
    for (int j = 0; j < NTOK; ++j)
        if (cs[j] == v) bidx[o++] = j;
    cntg[v] = cnts[v];
    offg[v] = offs[v];
}

// ------------------------------------------------------------------
// K4: exact top-k routes: sort by (|ci-cj|, j) ascending, take 128.
// one thread per query. 8 blocks x 256.
__global__ __launch_bounds__(256) void routes_k(const int* __restrict__ codes,
                                                const int* __restrict__ cntg,
                                                const int* __restrict__ offg,
                                                const int* __restrict__ bidxg,
                                                int* __restrict__ routes) {
    __shared__ int cnt_l[256];
    __shared__ int off_l[256];
    __shared__ int bidx_l[NTOK];
    int tid = threadIdx.x;
    cnt_l[tid] = cntg[tid];
    off_l[tid] = offg[tid];
    for (int j = tid; j < NTOK; j += 256) bidx_l[j] = bidxg[j];
    __syncthreads();

    int q = blockIdx.x * 256 + tid;
    int ci = codes[q];
    int* rout = routes + (size_t)q * KWIN;
    int need = KWIN;
    int pos = 0;
    for (int d = 0; d < 256 && need > 0; ++d) {
        int lo = ci - d, hi = ci + d;
        int cl = (lo >= 0) ? cnt_l[lo] : 0;
        int ch = (d > 0 && hi < 256) ? cnt_l[hi] : 0;
        int tot = cl + ch;
        if (tot == 0) continue;
        if (tot <= need) {
            for (int k = 0; k < cl; ++k) rout[pos++] = bidx_l[off_l[lo] + k];
            if (ch > 0)
                for (int k = 0; k < ch; ++k) rout[pos++] = bidx_l[off_l[hi] + k];
            need -= tot;
        } else {
            int il = 0, ih = 0;
            while (need > 0) {
                int jl = (il < cl) ? bidx_l[off_l[lo] + il] : 0x40000000;
                int jh = (ih < ch) ? bidx_l[off_l[hi] + ih] : 0x40000000;
                if (jl < jh) { rout[pos++] = jl; ++il; }
                else         { rout[pos++] = jh; ++ih; }
                --need;
            }
        }
    }
}

// ------------------------------------------------------------------
// K5/K7: C[M][Nn] = A[M][512] * B[Nn][512]^T + bias   (f32, 64x64 tile)
__global__ __launch_bounds__(256) void gemm_nt_bias(const float* __restrict__ A,
                                                    const float* __restrict__ Bw,
                                                    const float* __restrict__ bias,
                                                    float* __restrict__ Cc,
                                                    int M, int Nn) {
    __shared__ float As[32][68];
    __shared__ float Bs[32][68];
    int tid = threadIdx.x;
    int n0 = blockIdx.x * 64;
    int m0 = blockIdx.y * 64;
    int tm = tid & 15, tn = tid >> 4;
    float acc[4][4] = {};
    for (int k0 = 0; k0 < 512; k0 += 32) {
#pragma unroll
        for (int i = 0; i < 2; ++i) {
            int f = i * 256 + tid;
            int r = f >> 3, c4 = (f & 7) * 4;
            float4 va = *(const float4*)(A + (size_t)(m0 + r) * 512 + k0 + c4);
            As[c4 + 0][r] = va.x; As[c4 + 1][r] = va.y;
            As[c4 + 2][r] = va.z; As[c4 + 3][r] = va.w;
            float4 vb = *(const float4*)(Bw + (size_t)(n0 + r) * 512 + k0 + c4);
            Bs[c4 + 0][r] = vb.x; Bs[c4 + 1][r] = vb.y;
            Bs[c4 + 2][r] = vb.z; Bs[c4 + 3][r] = vb.w;
        }
        __syncthreads();
#pragma unroll
        for (int k = 0; k < 32; ++k) {
            float4 a4 = *(const float4*)&As[k][tm * 4];
            float4 b4 = *(const float4*)&Bs[k][tn * 4];
            float av[4] = {a4.x, a4.y, a4.z, a4.w};
            float bv[4] = {b4.x, b4.y, b4.z, b4.w};
#pragma unroll
            for (int i = 0; i < 4; ++i)
#pragma unroll
                for (int j = 0; j < 4; ++j) acc[i][j] += av[i] * bv[j];
        }
        __syncthreads();
    }
#pragma unroll
    for (int i = 0; i < 4; ++i) {
        int m = m0 + tm * 4 + i;
        int n = n0 + tn * 4;
        float4 o;
        o.x = acc[i][0] + bias[n + 0];
        o.y = acc[i][1] + bias[n + 1];
        o.z = acc[i][2] + bias[n + 2];
        o.w = acc[i][3] + bias[n + 3];
        *(float4*)(Cc + (size_t)m * Nn + n) = o;
    }
}

// ------------------------------------------------------------------
// K6: sparse attention per query. block = 1 query, 256 threads.
__global__ __launch_bounds__(256) void attn_k(const float* __restrict__ qkv,
                                              const int* __restrict__ routes,
                                              float* __restrict__ Obuf) {
    __shared__ int rt[KWIN];
    __shared__ float ql[DIM];
    __shared__ float sc[NHEAD][KWIN];
    int tid = threadIdx.x;
    int q = blockIdx.x;
    if (tid < KWIN) rt[tid] = routes[(size_t)q * KWIN + tid];
    for (int d = tid; d < DIM; d += 256) ql[d] = qkv[(size_t)q * 1536 + d];
    __syncthreads();

    // scores: 1024 dot products of length 64
#pragma unroll
    for (int rep = 0; rep < 4; ++rep) {
        int idx = rep * 256 + tid;
        int h = idx >> 7, kk = idx & 127;
        int j = rt[kk];
        const float* kp = qkv + (size_t)j * 1536 + 512 + h * 64;
        const float* qp = &ql[h * 64];
        float s = 0.f;
#pragma unroll
        for (int d = 0; d < 64; d += 4) {
            float4 kv = *(const float4*)(kp + d);
            float4 qv = *(const float4*)(qp + d);
            s += qv.x * kv.x + qv.y * kv.y + qv.z * kv.z + qv.w * kv.w;
        }
        sc[h][kk] = s * 0.125f;
    }
    __syncthreads();

    // softmax: 8 groups of 32 lanes, one head each
    {
        int g = tid >> 5, l = tid & 31;
        float v0 = sc[g][l], v1 = sc[g][l + 32], v2 = sc[g][l + 64], v3 = sc[g][l + 96];
        float mx = fmaxf(fmaxf(v0, v1), fmaxf(v2, v3));
        for (int m = 16; m; m >>= 1) mx = fmaxf(mx, __shfl_xor(mx, m, 32));
        float e0 = __expf(v0 - mx), e1 = __expf(v1 - mx),
              e2 = __expf(v2 - mx), e3 = __expf(v3 - mx);
        // use precise expf for safety
        e0 = expf(v0 - mx); e1 = expf(v1 - mx); e2 = expf(v2 - mx); e3 = expf(v3 - mx);
        float sum = e0 + e1 + e2 + e3;
        for (int m = 16; m; m >>= 1) sum += __shfl_xor(sum, m, 32);
        float inv = 1.f / sum;
        sc[g][l] = e0 * inv; sc[g][l + 32] = e1 * inv;
        sc[g][l + 64] = e2 * inv; sc[g][l + 96] = e3 * inv;
    }
    __syncthreads();

    // PV: thread handles (h, d) and (h+4, d)
    {
        int h = tid >> 6, d = tid & 63;
        float a0 = 0.f, a1 = 0.f;
        for (int kk = 0; kk < KWIN; ++kk) {
            int j = rt[kk];
            const float* vp = qkv + (size_t)j * 1536 + 1024;
            a0 += sc[h][kk] * vp[h * 64 + d];
            a1 += sc[h + 4][kk] * vp[(h + 4) * 64 + d];
        }
        Obuf[(size_t)q * DIM + h * 64 + d] = a0;
        Obuf[(size_t)q * DIM + (h + 4) * 64 + d] = a1;
    }
}

// ------------------------------------------------------------------
extern "C" void kernel_launch(void* const* d_in, const int* in_sizes, int n_in,
                              void* d_out, int out_size, void* d_ws, size_t ws_size,
                              hipStream_t stream) {
    const float* x      = (const float*)d_in[0];
    const float* penta  = (const float*)d_in[1];
    const float* w_qkv  = (const float*)d_in[2];
    const float* b_qkv  = (const float*)d_in[3];
    const float* w_out  = (const float*)d_in[4];
    const float* b_out  = (const float*)d_in[5];
    const float* gw     = (const float*)d_in[6];
    float* out = (float*)d_out;
    char* ws = (char*)d_ws;

    double* cenT = (double*)(ws + 0);
    int* codes   = (int*)(ws + 2097152);
    int* cnt     = (int*)(ws + 2105344);
    int* offs    = (int*)(ws + 2106368);
    int* bidx    = (int*)(ws + 2107392);
    int* routes  = (int*)(ws + 2115584);
    float* qkv   = (float*)(ws + 3164160);
    float* Obuf  = (float*)(ws + 15747072);

    centroids_k<<<512, 256, 0, stream>>>(penta, cenT);
    codes_k<<<256, 256, 0, stream>>>(x, cenT, gw, codes);
    bucket_k<<<1, 256, 0, stream>>>(codes, cnt, offs, bidx);
    routes_k<<<8, 256, 0, stream>>>(codes, cnt, offs, bidx, routes);
    gemm_nt_bias<<<dim3(1536 / 64, 2048 / 64), 256, 0, stream>>>(x, w_qkv, b_qkv, qkv, NTOK, 1536);
    attn_k<<<NTOK, 256, 0, stream>>>(qkv, routes, Obuf);
    gemm_nt_bias<<<dim3(512 / 64, 2048 / 64), 256, 0, stream>>>(Obuf, w_out, b_out, out, NTOK, 512);
}

// Round 2
// 342.311 us; speedup vs baseline: 1.7203x; 1.7203x over previous
//
#include <hip/hip_runtime.h>
#include <hip/hip_bf16.h>
#include <math.h>

// Problem constants (fixed instance)
#define NTOK 2048
#define DIM 512
#define NCEN 500
#define NHEAD 8
#define HD 64
#define KWIN 128
#define DEPTH 8

// ---------------- workspace layout (bytes) ----------------
// cenT    f64 [512][512]      @ 0          (2 MB) (cols >=500 zero)
// codes   i32 [2048]          @ 2097152
// P       i32 [257]           @ 2105344    (prefix sum of bucket sizes)
// bidx    i32 [2048]          @ 2106400    (tokens sorted by (code, idx))
// hist    i32 [8][256]        @ 2115584    (overlaps routes head - dead before routes written)
// chunkoff i32 [8][256]       @ 2123776    (overlaps routes - dead before routes written)
// routes  i32 [2048][128]     @ 2115584    (1 MB)
// qkv     f32 [2048][1536]    @ 3164160    (12 MB)
// Obuf    f32 [2048][512]     @ 15747072   (4 MB)

// ------------------------------------------------------------------
// K1: centroids transposed, f64.  cenT[d][c] = mean_v p[c][v][d]
__global__ __launch_bounds__(256) void centroids_k(const float* __restrict__ p,
                                                   double* __restrict__ cenT) {
    int c = blockIdx.x;
    for (int d = threadIdx.x; d < DIM; d += 256) {
        double s = 0.0;
        if (c < NCEN) {
            const float* pc = p + (size_t)c * 5 * DIM;
        s  = (double)pc[0 * DIM + d];
        s += (double)pc[1 * DIM + d];
        s += (double)pc[2 * DIM + d];
        s += (double)pc[3 * DIM + d];
        s += (double)pc[4 * DIM + d];
            s = s / 5.0;
        }
        cenT[(size_t)d * 512 + c] = s;
    }
}

// ------------------------------------------------------------------
// K2: cantor integer codes, all in f64.
__global__ __launch_bounds__(256) void codes_k(const float* __restrict__ x,
                                               const double* __restrict__ cenT,
                                               const float* __restrict__ gwp,
                                               int* __restrict__ codes) {
    __shared__ double xs[8][DIM];   // 32 KB
    __shared__ double red[256];
    __shared__ double nrm[8];
    int tid = threadIdx.x;
    int tok0 = blockIdx.x * 8;

    for (int t = 0; t < 8; ++t)
        for (int d = tid; d < DIM; d += 256)
            xs[t][d] = (double)x[(size_t)(tok0 + t) * DIM + d];
    __syncthreads();

    {
        int g = tid >> 5, l = tid & 31;
        double ss = 0.0;
        for (int d = l; d < DIM; d += 32) ss += xs[g][d] * xs[g][d];
        for (int m = 16; m; m >>= 1) ss += __shfl_xor(ss, m, 32);
        if (l == 0) nrm[g] = sqrt(ss) + 1e-12;
    }
    __syncthreads();
    for (int t = 0; t < 8; ++t)
        for (int d = tid; d < DIM; d += 256)
            xs[t][d] = xs[t][d] / nrm[t];
    __syncthreads();

    int c0 = tid, c1 = tid + 256;
    double acc[8][2];
#pragma unroll
    for (int t = 0; t < 8; ++t) { acc[t][0] = 0.0; acc[t][1] = 0.0; }
    for (int d = 0; d < DIM; ++d) {
        double e0 = cenT[(size_t)d * 512 + c0];
        double e1 = cenT[(size_t)d * 512 + c1];
#pragma unroll
        for (int t = 0; t < 8; ++t) {
            double xv = xs[t][d];
            acc[t][0] += xv * e0;
            acc[t][1] += xv * e1;
        }
    }

    double gwv = 1.0 / (1.0 + exp(-(double)gwp[0]));
    const double delta = 1.0 / 2047.0;

    for (int t = 0; t < 8; ++t) {
        double m0 = acc[t][0];
        if (c1 < NCEN) m0 = fmax(m0, acc[t][1]);
        red[tid] = m0;
        __syncthreads();
        for (int s = 128; s > 0; s >>= 1) {
            if (tid < s) red[tid] = fmax(red[tid], red[tid + s]);
            __syncthreads();
        }
        if (tid == 0) {
            int n = tok0 + t;
            double gd = 1.0 - red[0];
            double pos = (n == NTOK - 1) ? 1.0 : (double)n * delta;
            double xc = pos * (1.0 - gwv) + gd * gwv;
            xc = fmin(fmax(xc, 1e-6), 1.0 - 1e-6);
            int code = 0;
#pragma unroll
            for (int l = 0; l < DEPTH; ++l) {
                double s3 = xc * 3.0;
                double dig = floor(s3);
                if (dig == 2.0) code |= 1 << (7 - l);
                xc = s3 - dig;
            }
            codes[n] = code;
        }
        __syncthreads();
    }
}

// ------------------------------------------------------------------
// K3a: per-chunk histogram. 8 blocks x 256.
__global__ __launch_bounds__(256) void hist_k(const int* __restrict__ codes,
                                              int* __restrict__ hist) {
    __shared__ int hl[256];
    int tid = threadIdx.x;
    hl[tid] = 0;
    __syncthreads();
    int c = codes[blockIdx.x * 256 + tid];
    atomicAdd(&hl[c], 1);
    __syncthreads();
    hist[blockIdx.x * 256 + tid] = hl[tid];
}

// K3b: scan -> P[257] and per-chunk offsets. 1 block x 256.
__global__ __launch_bounds__(256) void scan_k(const int* __restrict__ hist,
                                              int* __restrict__ P,
                                              int* __restrict__ chunkoff) {
    __shared__ int sc[256];
    int c = threadIdx.x;
    int h[8];
    int t = 0;
#pragma unroll
    for (int b = 0; b < 8; ++b) { h[b] = hist[b * 256 + c]; t += h[b]; }
    sc[c] = t;
    __syncthreads();
    for (int off = 1; off < 256; off <<= 1) {
        int v = sc[c];
        int add = (c >= off) ? sc[c - off] : 0;
        __syncthreads();
        sc[c] = v + add;
        __syncthreads();
    }
    int incl = sc[c];
    int base = incl - t;
    P[c] = base;
    if (c == 255) P[256] = incl;   // == 2048
    int pre = base;
#pragma unroll
    for (int b = 0; b < 8; ++b) { chunkoff[b * 256 + c] = pre; pre += h[b]; }
}

// K3c: stable scatter. 8 blocks x 256.
__global__ __launch_bounds__(256) void scatter_k(const int* __restrict__ codes,
                                                 const int* __restrict__ chunkoff,
                                                 int* __restrict__ bidx) {
    __shared__ int cl[256];
    int tid = threadIdx.x;
    int b = blockIdx.x;
    int idx = b * 256 + tid;
    int c = codes[idx];
    cl[tid] = c;
    __syncthreads();
    int rank = 0;
    for (int j = 0; j < tid; ++j) rank += (cl[j] == c) ? 1 : 0;
    bidx[chunkoff[b * 256 + c] + rank] = idx;
}

// ------------------------------------------------------------------
// K4: routes, one wave (64 lanes) per query. 512 blocks x 256 (4 waves).
// Selection set = all tokens with |code - ci| < d*  (contiguous slice of bidx)
//               + rem smallest-index tokens from boundary buckets ci-d*, ci+d*.
// Route ORDER does not matter (softmax+PV are permutation-invariant).
__global__ __launch_bounds__(256) void routes2_k(const int* __restrict__ codes,
                                                 const int* __restrict__ P,
                                                 const int* __restrict__ bidx,
                                                 int* __restrict__ routes) {
    int tid = threadIdx.x;
    int lane = tid & 63;
    int w = tid >> 6;
    int q = blockIdx.x * 4 + w;
    int ci = codes[q];

    // find d* = min d with cumulative window count >= KWIN
    int dstar = -1;
    for (int r = 0; r < 4 && dstar < 0; ++r) {
        int d = r * 64 + lane;
        int loc = ci - d; if (loc < 0) loc = 0;
        int hic = ci + d; if (hic > 255) hic = 255;
        int cum = P[hic + 1] - P[loc];
        unsigned long long m = __ballot(cum >= KWIN);
        if (m) dstar = r * 64 + (int)__builtin_ctzll(m);
    }

    int a = ci - dstar + 1; if (a < 0) a = 0;
    int b = ci + dstar - 1; if (b > 255) b = 255;
    int inner = 0, baseA = 0;
    if (dstar > 0) { baseA = P[a]; inner = P[b + 1] - baseA; }
    int rem = KWIN - inner;
    int* rq = routes + (size_t)q * KWIN;

    for (int t = lane; t < inner; t += 64) rq[t] = bidx[baseA + t];

    // boundary buckets
    int lo = ci - dstar, hi = ci + dstar;
    int loS = 0, loL = 0, hiS = 0, hiL = 0;
    if (lo >= 0) { loS = P[lo]; loL = P[lo + 1] - loS; }
    if (dstar > 0 && hi <= 255) { hiS = P[hi]; hiL = P[hi + 1] - hiS; }
    // (dstar==0: single bucket ci handled by lo path, hiL=0)

    int minI = rem - hiL; if (minI < 0) minI = 0;
    int maxI = (rem < loL) ? rem : loL;
    // binary search split: take ilo from lo-list, rem-ilo from hi-list
    // (all lanes redundantly; same data, broadcast loads)
    int ans = minI;
    int loI = minI, hiI = maxI;
    for (int it = 0; it < 12 && loI <= hiI; ++it) {
        int i = (loI + hiI) >> 1;
        int j = rem - i;
        bool tooMany = (i > 0 && j < hiL && bidx[loS + i - 1] > bidx[hiS + j]);
        bool tooFew  = (j > 0 && i < loL && bidx[hiS + j - 1] > bidx[loS + i]);
        if (tooMany) hiI = i - 1;
        else if (tooFew) loI = i + 1;
        else { ans = i; break; }
    }
    int ilo = ans;
    int jn = rem - ilo;
    for (int t = lane; t < ilo; t += 64) rq[inner + t] = bidx[loS + t];
    for (int t = lane; t < jn; t += 64) rq[inner + ilo + t] = bidx[hiS + t];
}

// ------------------------------------------------------------------
// K5/K7: C[M][Nn] = A[M][512] * B[Nn][512]^T + bias   (f32, 64x64 tile)
__global__ __launch_bounds__(256) void gemm_nt_bias(const float* __restrict__ A,
                                                    const float* __restrict__ Bw,
                                                    const float* __restrict__ bias,
                                                    float* __restrict__ Cc,
                                                    int M, int Nn) {
    __shared__ float As[32][68];
    __shared__ float Bs[32][68];
    int tid = threadIdx.x;
    int n0 = blockIdx.x * 64;
    int m0 = blockIdx.y * 64;
    int tm = tid & 15, tn = tid >> 4;
    float acc[4][4] = {};
    for (int k0 = 0; k0 < 512; k0 += 32) {
#pragma unroll
        for (int i = 0; i < 2; ++i) {
            int f = i * 256 + tid;
            int r = f >> 3, c4 = (f & 7) * 4;
            float4 va = *(const float4*)(A + (size_t)(m0 + r) * 512 + k0 + c4);
            As[c4 + 0][r] = va.x; As[c4 + 1][r] = va.y;
            As[c4 + 2][r] = va.z; As[c4 + 3][r] = va.w;
            float4 vb = *(const float4*)(Bw + (size_t)(n0 + r) * 512 + k0 + c4);
            Bs[c4 + 0][r] = vb.x; Bs[c4 + 1][r] = vb.y;
            Bs[c4 + 2][r] = vb.z; Bs[c4 + 3][r] = vb.w;
        }
        __syncthreads();
#pragma unroll
        for (int k = 0; k < 32; ++k) {
            float4 a4 = *(const float4*)&As[k][tm * 4];
            float4 b4 = *(const float4*)&Bs[k][tn * 4];
            float av[4] = {a4.x, a4.y, a4.z, a4.w};
            float bv[4] = {b4.x, b4.y, b4.z, b4.w};
#pragma unroll
            for (int i = 0; i < 4; ++i)
#pragma unroll
                for (int j = 0; j < 4; ++j) acc[i][j] += av[i] * bv[j];
        }
        __syncthreads();
    }
#pragma unroll
    for (int i = 0; i < 4; ++i) {
        int m = m0 + tm * 4 + i;
        int n = n0 + tn * 4;
        float4 o;
        o.x = acc[i][0] + bias[n + 0];
        o.y = acc[i][1] + bias[n + 1];
        o.z = acc[i][2] + bias[n + 2];
        o.w = acc[i][3] + bias[n + 3];
        *(float4*)(Cc + (size_t)m * Nn + n) = o;
    }
}

// ------------------------------------------------------------------
// K6: sparse attention per query. block = 1 query, 256 threads.
__global__ __launch_bounds__(256) void attn_k(const float* __restrict__ qkv,
                                              const int* __restrict__ routes,
                                              float* __restrict__ Obuf) {
    __shared__ int rt[KWIN];
    __shared__ float ql[DIM];
    __shared__ float sc[NHEAD][KWIN];
    int tid = threadIdx.x;
    int q = blockIdx.x;
    if (tid < KWIN) rt[tid] = routes[(size_t)q * KWIN + tid];
    for (int d = tid; d < DIM; d += 256) ql[d] = qkv[(size_t)q * 1536 + d];
    __syncthreads();

#pragma unroll
    for (int rep = 0; rep < 4; ++rep) {
        int idx = rep * 256 + tid;
        int h = idx >> 7, kk = idx & 127;
        int j = rt[kk];
        const float* kp = qkv + (size_t)j * 1536 + 512 + h * 64;
        const float* qp = &ql[h * 64];
        float s = 0.f;
#pragma unroll
        for (int d = 0; d < 64; d += 4) {
            float4 kv = *(const float4*)(kp + d);
            float4 qv = *(const float4*)(qp + d);
            s += qv.x * kv.x + qv.y * kv.y + qv.z * kv.z + qv.w * kv.w;
        }
        sc[h][kk] = s * 0.125f;
    }
    __syncthreads();

    {
        int g = tid >> 5, l = tid & 31;
        float v0 = sc[g][l], v1 = sc[g][l + 32], v2 = sc[g][l + 64], v3 = sc[g][l + 96];
        float mx = fmaxf(fmaxf(v0, v1), fmaxf(v2, v3));
        for (int m = 16; m; m >>= 1) mx = fmaxf(mx, __shfl_xor(mx, m, 32));
        float e0 = expf(v0 - mx), e1 = expf(v1 - mx),
              e2 = expf(v2 - mx), e3 = expf(v3 - mx);
        float sum = e0 + e1 + e2 + e3;
        for (int m = 16; m; m >>= 1) sum += __shfl_xor(sum, m, 32);
        float inv = 1.f / sum;
        sc[g][l] = e0 * inv; sc[g][l + 32] = e1 * inv;
        sc[g][l + 64] = e2 * inv; sc[g][l + 96] = e3 * inv;
    }
    __syncthreads();

    {
        int h = tid >> 6, d = tid & 63;
        float a0 = 0.f, a1 = 0.f;
        for (int kk = 0; kk < KWIN; ++kk) {
            int j = rt[kk];
            const float* vp = qkv + (size_t)j * 1536 + 1024;
            a0 += sc[h][kk] * vp[h * 64 + d];
            a1 += sc[h + 4][kk] * vp[(h + 4) * 64 + d];
        }
        Obuf[(size_t)q * DIM + h * 64 + d] = a0;
        Obuf[(size_t)q * DIM + (h + 4) * 64 + d] = a1;
    }
}

// ------------------------------------------------------------------
extern "C" void kernel_launch(void* const* d_in, const int* in_sizes, int n_in,
                              void* d_out, int out_size, void* d_ws, size_t ws_size,
                              hipStream_t stream) {
    const float* x      = (const float*)d_in[0];
    const float* penta  = (const float*)d_in[1];
    const float* w_qkv  = (const float*)d_in[2];
    const float* b_qkv  = (const float*)d_in[3];
    const float* w_out  = (const float*)d_in[4];
    const float* b_out  = (const float*)d_in[5];
    const float* gw     = (const float*)d_in[6];
    float* out = (float*)d_out;
    char* ws = (char*)d_ws;

    double* cenT  = (double*)(ws + 0);
    int* codes    = (int*)(ws + 2097152);
    int* P        = (int*)(ws + 2105344);
    int* bidx     = (int*)(ws + 2106400);
    int* hist     = (int*)(ws + 2115584);   // overlaps routes head (dead before routes written)
    int* chunkoff = (int*)(ws + 2123776);   // overlaps routes (dead before routes written)
    int* routes   = (int*)(ws + 2115584);
    float* qkv    = (float*)(ws + 3164160);
    float* Obuf   = (float*)(ws + 15747072);

    centroids_k<<<512, 256, 0, stream>>>(penta, cenT);
    codes_k<<<256, 256, 0, stream>>>(x, cenT, gw, codes);
    hist_k<<<8, 256, 0, stream>>>(codes, hist);
    scan_k<<<1, 256, 0, stream>>>(hist, P, chunkoff);
    scatter_k<<<8, 256, 0, stream>>>(codes, chunkoff, bidx);
    gemm_nt_bias<<<dim3(1536 / 64, 2048 / 64), 256, 0, stream>>>(x, w_qkv, b_qkv, qkv, NTOK, 1536);
    routes2_k<<<512, 256, 0, stream>>>(codes, P, bidx, routes);
    attn_k<<<NTOK, 256, 0, stream>>>(qkv, routes, Obuf);
    gemm_nt_bias<<<dim3(512 / 64, 2048 / 64), 256, 0, stream>>>(Obuf, w_out, b_out, out, NTOK, 512);
}

// Round 3
// 276.017 us; speedup vs baseline: 2.1335x; 1.2402x over previous
//
#include <hip/hip_runtime.h>
#include <hip/hip_bf16.h>
#include <math.h>

// Problem constants (fixed instance)
#define NTOK 2048
#define DIM 512
#define NCEN 500
#define NHEAD 8
#define HD 64
#define KWIN 128
#define DEPTH 8

// ---------------- workspace layout (bytes) ----------------
// cenT    f64 [512][512]      @ 0          (2 MB) (cols >=500 zero)
// codes   i32 [2048]          @ 2097152
// P       i32 [257]           @ 2105344    (prefix sum of bucket sizes)
// bidx    i32 [2048]          @ 2106400    (tokens sorted by (code, idx))
// hist    i32 [8][256]        @ 2115584    (overlaps routes head - dead before routes written)
// chunkoff i32 [8][256]       @ 2123776    (overlaps routes - dead before routes written)
// routes  i32 [2048][128]     @ 2115584    (1 MB)
// qkv     f32 [2048][1536]    @ 3164160    (12 MB)
// Obuf    f32 [2048][512]     @ 15747072   (4 MB)

// ------------------------------------------------------------------
// K1: centroids transposed, f64.  cenT[d][c] = mean_v p[c][v][d]
__global__ __launch_bounds__(256) void centroids_k(const float* __restrict__ p,
                                                   double* __restrict__ cenT) {
    int c = blockIdx.x;
    for (int d = threadIdx.x; d < DIM; d += 256) {
        double s = 0.0;
        if (c < NCEN) {
            const float* pc = p + (size_t)c * 5 * DIM;
            s  = (double)pc[0 * DIM + d];
            s += (double)pc[1 * DIM + d];
            s += (double)pc[2 * DIM + d];
            s += (double)pc[3 * DIM + d];
            s += (double)pc[4 * DIM + d];
            s = s / 5.0;
        }
        cenT[(size_t)d * 512 + c] = s;
    }
}

// ------------------------------------------------------------------
// K2: cantor integer codes, all in f64.
__global__ __launch_bounds__(256) void codes_k(const float* __restrict__ x,
                                               const double* __restrict__ cenT,
                                               const float* __restrict__ gwp,
                                               int* __restrict__ codes) {
    __shared__ double xs[8][DIM];   // 32 KB
    __shared__ double red[256];
    __shared__ double nrm[8];
    int tid = threadIdx.x;
    int tok0 = blockIdx.x * 8;

    for (int t = 0; t < 8; ++t)
        for (int d = tid; d < DIM; d += 256)
            xs[t][d] = (double)x[(size_t)(tok0 + t) * DIM + d];
    __syncthreads();

    {
        int g = tid >> 5, l = tid & 31;
        double ss = 0.0;
        for (int d = l; d < DIM; d += 32) ss += xs[g][d] * xs[g][d];
        for (int m = 16; m; m >>= 1) ss += __shfl_xor(ss, m, 32);
        if (l == 0) nrm[g] = sqrt(ss) + 1e-12;
    }
    __syncthreads();
    for (int t = 0; t < 8; ++t)
        for (int d = tid; d < DIM; d += 256)
            xs[t][d] = xs[t][d] / nrm[t];
    __syncthreads();

    int c0 = tid, c1 = tid + 256;
    double acc[8][2];
#pragma unroll
    for (int t = 0; t < 8; ++t) { acc[t][0] = 0.0; acc[t][1] = 0.0; }
    for (int d = 0; d < DIM; ++d) {
        double e0 = cenT[(size_t)d * 512 + c0];
        double e1 = cenT[(size_t)d * 512 + c1];
#pragma unroll
        for (int t = 0; t < 8; ++t) {
            double xv = xs[t][d];
            acc[t][0] += xv * e0;
            acc[t][1] += xv * e1;
        }
    }

    double gwv = 1.0 / (1.0 + exp(-(double)gwp[0]));
    const double delta = 1.0 / 2047.0;

    for (int t = 0; t < 8; ++t) {
        double m0 = acc[t][0];
        if (c1 < NCEN) m0 = fmax(m0, acc[t][1]);
        red[tid] = m0;
        __syncthreads();
        for (int s = 128; s > 0; s >>= 1) {
            if (tid < s) red[tid] = fmax(red[tid], red[tid + s]);
            __syncthreads();
        }
        if (tid == 0) {
            int n = tok0 + t;
            double gd = 1.0 - red[0];
            double pos = (n == NTOK - 1) ? 1.0 : (double)n * delta;
            double xc = pos * (1.0 - gwv) + gd * gwv;
            xc = fmin(fmax(xc, 1e-6), 1.0 - 1e-6);
            int code = 0;
#pragma unroll
            for (int l = 0; l < DEPTH; ++l) {
                double s3 = xc * 3.0;
                double dig = floor(s3);
                if (dig == 2.0) code |= 1 << (7 - l);
                xc = s3 - dig;
            }
            codes[n] = code;
        }
        __syncthreads();
    }
}

// ------------------------------------------------------------------
// K3a: per-chunk histogram. 8 blocks x 256.
__global__ __launch_bounds__(256) void hist_k(const int* __restrict__ codes,
                                              int* __restrict__ hist) {
    __shared__ int hl[256];
    int tid = threadIdx.x;
    hl[tid] = 0;
    __syncthreads();
    int c = codes[blockIdx.x * 256 + tid];
    atomicAdd(&hl[c], 1);
    __syncthreads();
    hist[blockIdx.x * 256 + tid] = hl[tid];
}

// K3b: scan -> P[257] and per-chunk offsets. 1 block x 256.
__global__ __launch_bounds__(256) void scan_k(const int* __restrict__ hist,
                                              int* __restrict__ P,
                                              int* __restrict__ chunkoff) {
    __shared__ int sc[256];
    int c = threadIdx.x;
    int h[8];
    int t = 0;
#pragma unroll
    for (int b = 0; b < 8; ++b) { h[b] = hist[b * 256 + c]; t += h[b]; }
    sc[c] = t;
    __syncthreads();
    for (int off = 1; off < 256; off <<= 1) {
        int v = sc[c];
        int add = (c >= off) ? sc[c - off] : 0;
        __syncthreads();
        sc[c] = v + add;
        __syncthreads();
    }
    int incl = sc[c];
    int base = incl - t;
    P[c] = base;
    if (c == 255) P[256] = incl;   // == 2048
    int pre = base;
#pragma unroll
    for (int b = 0; b < 8; ++b) { chunkoff[b * 256 + c] = pre; pre += h[b]; }
}

// K3c: stable scatter. 8 blocks x 256.
__global__ __launch_bounds__(256) void scatter_k(const int* __restrict__ codes,
                                                 const int* __restrict__ chunkoff,
                                                 int* __restrict__ bidx) {
    __shared__ int cl[256];
    int tid = threadIdx.x;
    int b = blockIdx.x;
    int idx = b * 256 + tid;
    int c = codes[idx];
    cl[tid] = c;
    __syncthreads();
    int rank = 0;
    for (int j = 0; j < tid; ++j) rank += (cl[j] == c) ? 1 : 0;
    bidx[chunkoff[b * 256 + c] + rank] = idx;
}

// ------------------------------------------------------------------
// K4: routes, one wave (64 lanes) per query. 512 blocks x 256 (4 waves).
// Selection set = all tokens with |code - ci| < d*  (contiguous slice of bidx)
//               + rem smallest-index tokens from boundary buckets ci-d*, ci+d*.
// Route ORDER does not matter (softmax+PV are permutation-invariant).
__global__ __launch_bounds__(256) void routes2_k(const int* __restrict__ codes,
                                                 const int* __restrict__ P,
                                                 const int* __restrict__ bidx,
                                                 int* __restrict__ routes) {
    int tid = threadIdx.x;
    int lane = tid & 63;
    int w = tid >> 6;
    int q = blockIdx.x * 4 + w;
    int ci = codes[q];

    int dstar = -1;
    for (int r = 0; r < 4 && dstar < 0; ++r) {
        int d = r * 64 + lane;
        int loc = ci - d; if (loc < 0) loc = 0;
        int hic = ci + d; if (hic > 255) hic = 255;
        int cum = P[hic + 1] - P[loc];
        unsigned long long m = __ballot(cum >= KWIN);
        if (m) dstar = r * 64 + (int)__builtin_ctzll(m);
    }

    int a = ci - dstar + 1; if (a < 0) a = 0;
    int b = ci + dstar - 1; if (b > 255) b = 255;
    int inner = 0, baseA = 0;
    if (dstar > 0) { baseA = P[a]; inner = P[b + 1] - baseA; }
    int rem = KWIN - inner;
    int* rq = routes + (size_t)q * KWIN;

    for (int t = lane; t < inner; t += 64) rq[t] = bidx[baseA + t];

    int lo = ci - dstar, hi = ci + dstar;
    int loS = 0, loL = 0, hiS = 0, hiL = 0;
    if (lo >= 0) { loS = P[lo]; loL = P[lo + 1] - loS; }
    if (dstar > 0 && hi <= 255) { hiS = P[hi]; hiL = P[hi + 1] - hiS; }

    int minI = rem - hiL; if (minI < 0) minI = 0;
    int maxI = (rem < loL) ? rem : loL;
    int ans = minI;
    int loI = minI, hiI = maxI;
    for (int it = 0; it < 12 && loI <= hiI; ++it) {
        int i = (loI + hiI) >> 1;
        int j = rem - i;
        bool tooMany = (i > 0 && j < hiL && bidx[loS + i - 1] > bidx[hiS + j]);
        bool tooFew  = (j > 0 && i < loL && bidx[hiS + j - 1] > bidx[loS + i]);
        if (tooMany) hiI = i - 1;
        else if (tooFew) loI = i + 1;
        else { ans = i; break; }
    }
    int ilo = ans;
    int jn = rem - ilo;
    for (int t = lane; t < ilo; t += 64) rq[inner + t] = bidx[loS + t];
    for (int t = lane; t < jn; t += 64) rq[inner + ilo + t] = bidx[hiS + t];
}

// ------------------------------------------------------------------
// K5/K7: C[M][Nn] = A[M][512] * B[Nn][512]^T + bias   (f32, 64x64 tile)
__global__ __launch_bounds__(256) void gemm_nt_bias(const float* __restrict__ A,
                                                    const float* __restrict__ Bw,
                                                    const float* __restrict__ bias,
                                                    float* __restrict__ Cc,
                                                    int M, int Nn) {
    __shared__ float As[32][68];
    __shared__ float Bs[32][68];
    int tid = threadIdx.x;
    int n0 = blockIdx.x * 64;
    int m0 = blockIdx.y * 64;
    int tm = tid & 15, tn = tid >> 4;
    float acc[4][4] = {};
    for (int k0 = 0; k0 < 512; k0 += 32) {
#pragma unroll
        for (int i = 0; i < 2; ++i) {
            int f = i * 256 + tid;
            int r = f >> 3, c4 = (f & 7) * 4;
            float4 va = *(const float4*)(A + (size_t)(m0 + r) * 512 + k0 + c4);
            As[c4 + 0][r] = va.x; As[c4 + 1][r] = va.y;
            As[c4 + 2][r] = va.z; As[c4 + 3][r] = va.w;
            float4 vb = *(const float4*)(Bw + (size_t)(n0 + r) * 512 + k0 + c4);
            Bs[c4 + 0][r] = vb.x; Bs[c4 + 1][r] = vb.y;
            Bs[c4 + 2][r] = vb.z; Bs[c4 + 3][r] = vb.w;
        }
        __syncthreads();
#pragma unroll
        for (int k = 0; k < 32; ++k) {
            float4 a4 = *(const float4*)&As[k][tm * 4];
            float4 b4 = *(const float4*)&Bs[k][tn * 4];
            float av[4] = {a4.x, a4.y, a4.z, a4.w};
            float bv[4] = {b4.x, b4.y, b4.z, b4.w};
#pragma unroll
            for (int i = 0; i < 4; ++i)
#pragma unroll
                for (int j = 0; j < 4; ++j) acc[i][j] += av[i] * bv[j];
        }
        __syncthreads();
    }
#pragma unroll
    for (int i = 0; i < 4; ++i) {
        int m = m0 + tm * 4 + i;
        int n = n0 + tn * 4;
        float4 o;
        o.x = acc[i][0] + bias[n + 0];
        o.y = acc[i][1] + bias[n + 1];
        o.z = acc[i][2] + bias[n + 2];
        o.w = acc[i][3] + bias[n + 3];
        *(float4*)(Cc + (size_t)m * Nn + n) = o;
    }
}

// ------------------------------------------------------------------
// K6 v3: sparse attention, row-streaming. 1 block = 1 query (in Cantor-sorted
// order via bidx, XCD-chunked for L2 locality). 256 threads = 4 waves.
// Wave w handles route slots [w*32, w*32+32). Lane owns 8 dims of head lane>>3.
// Scores: wave streams full 2KB K rows (contiguous) and reduces via shfl_xor.
// PV: per-lane 8-wide accumulators, cross-wave LDS reduction at the end.
__global__ __launch_bounds__(256) void attn_v3(const float* __restrict__ qkv,
                                               const int* __restrict__ bidx,
                                               const int* __restrict__ routes,
                                               float* __restrict__ Obuf) {
    __shared__ int rt[KWIN];
    __shared__ float sc[NHEAD][KWIN];
    __shared__ float part[4][DIM];
    int tid = threadIdx.x;
    int lane = tid & 63;
    int w = tid >> 6;

    int b = blockIdx.x;
    int ord = (b & 7) * 256 + (b >> 3);    // XCD-chunked, bijective on [0,2048)
    int q = bidx[ord];

    if (tid < KWIN) rt[tid] = routes[(size_t)q * KWIN + tid];

    // per-lane Q segment: 8 dims of head lane>>3
    const float* qrow = qkv + (size_t)q * 1536 + lane * 8;
    float4 qa = *(const float4*)(qrow);
    float4 qb = *(const float4*)(qrow + 4);
    __syncthreads();

    // ---- scores: stream K rows ----
#pragma unroll 4
    for (int i = 0; i < 32; ++i) {
        int kk = w * 32 + i;
        int j = rt[kk];
        const float* kp = qkv + (size_t)j * 1536 + 512 + lane * 8;
        float4 k0 = *(const float4*)(kp);
        float4 k1 = *(const float4*)(kp + 4);
        float s = qa.x * k0.x + qa.y * k0.y + qa.z * k0.z + qa.w * k0.w
                + qb.x * k1.x + qb.y * k1.y + qb.z * k1.z + qb.w * k1.w;
        s += __shfl_xor(s, 1);
        s += __shfl_xor(s, 2);
        s += __shfl_xor(s, 4);
        if ((lane & 7) == 0) sc[lane >> 3][kk] = s * 0.125f;
    }
    __syncthreads();

    // ---- softmax: 8 groups of 32 threads, one head each ----
    {
        int g = tid >> 5, l = tid & 31;
        float v0 = sc[g][l], v1 = sc[g][l + 32], v2 = sc[g][l + 64], v3 = sc[g][l + 96];
        float mx = fmaxf(fmaxf(v0, v1), fmaxf(v2, v3));
        for (int m = 16; m; m >>= 1) mx = fmaxf(mx, __shfl_xor(mx, m, 32));
        float e0 = expf(v0 - mx), e1 = expf(v1 - mx),
              e2 = expf(v2 - mx), e3 = expf(v3 - mx);
        float sum = e0 + e1 + e2 + e3;
        for (int m = 16; m; m >>= 1) sum += __shfl_xor(sum, m, 32);
        float inv = 1.f / sum;
        sc[g][l] = e0 * inv; sc[g][l + 32] = e1 * inv;
        sc[g][l + 64] = e2 * inv; sc[g][l + 96] = e3 * inv;
    }
    __syncthreads();

    // ---- PV: stream V rows ----
    float acc[8] = {0.f, 0.f, 0.f, 0.f, 0.f, 0.f, 0.f, 0.f};
    const float* sch = sc[lane >> 3];
#pragma unroll 4
    for (int i = 0; i < 32; ++i) {
        int kk = w * 32 + i;
        int j = rt[kk];
        float wgt = sch[kk];                       // LDS broadcast within 8-lane group
        const float* vp = qkv + (size_t)j * 1536 + 1024 + lane * 8;
        float4 v0 = *(const float4*)(vp);
        float4 v1 = *(const float4*)(vp + 4);
        acc[0] += wgt * v0.x; acc[1] += wgt * v0.y;
        acc[2] += wgt * v0.z; acc[3] += wgt * v0.w;
        acc[4] += wgt * v1.x; acc[5] += wgt * v1.y;
        acc[6] += wgt * v1.z; acc[7] += wgt * v1.w;
    }
#pragma unroll
    for (int e = 0; e < 8; ++e) part[w][lane * 8 + e] = acc[e];
    __syncthreads();

    // cross-wave reduce + write: 256 threads x 2 outputs
#pragma unroll
    for (int r = 0; r < 2; ++r) {
        int d = r * 256 + tid;
        float o = part[0][d] + part[1][d] + part[2][d] + part[3][d];
        Obuf[(size_t)q * DIM + d] = o;
    }
}

// ------------------------------------------------------------------
extern "C" void kernel_launch(void* const* d_in, const int* in_sizes, int n_in,
                              void* d_out, int out_size, void* d_ws, size_t ws_size,
                              hipStream_t stream) {
    const float* x      = (const float*)d_in[0];
    const float* penta  = (const float*)d_in[1];
    const float* w_qkv  = (const float*)d_in[2];
    const float* b_qkv  = (const float*)d_in[3];
    const float* w_out  = (const float*)d_in[4];
    const float* b_out  = (const float*)d_in[5];
    const float* gw     = (const float*)d_in[6];
    float* out = (float*)d_out;
    char* ws = (char*)d_ws;

    double* cenT  = (double*)(ws + 0);
    int* codes    = (int*)(ws + 2097152);
    int* P        = (int*)(ws + 2105344);
    int* bidx     = (int*)(ws + 2106400);
    int* hist     = (int*)(ws + 2115584);   // overlaps routes head (dead before routes written)
    int* chunkoff = (int*)(ws + 2123776);   // overlaps routes (dead before routes written)
    int* routes   = (int*)(ws + 2115584);
    float* qkv    = (float*)(ws + 3164160);
    float* Obuf   = (float*)(ws + 15747072);

    centroids_k<<<512, 256, 0, stream>>>(penta, cenT);
    codes_k<<<256, 256, 0, stream>>>(x, cenT, gw, codes);
    hist_k<<<8, 256, 0, stream>>>(codes, hist);
    scan_k<<<1, 256, 0, stream>>>(hist, P, chunkoff);
    scatter_k<<<8, 256, 0, stream>>>(codes, chunkoff, bidx);
    gemm_nt_bias<<<dim3(1536 / 64, 2048 / 64), 256, 0, stream>>>(x, w_qkv, b_qkv, qkv, NTOK, 1536);
    routes2_k<<<512, 256, 0, stream>>>(codes, P, bidx, routes);
    attn_v3<<<NTOK, 256, 0, stream>>>(qkv, bidx, routes, Obuf);
    gemm_nt_bias<<<dim3(512 / 64, 2048 / 64), 256, 0, stream>>>(Obuf, w_out, b_out, out, NTOK, 512);
}

// Round 4
// 263.341 us; speedup vs baseline: 2.2362x; 1.0481x over previous
//
#include <hip/hip_runtime.h>
#include <hip/hip_bf16.h>
#include <math.h>

// Problem constants (fixed instance)
#define NTOK 2048
#define DIM 512
#define NCEN 500
#define NHEAD 8
#define HD 64
#define KWIN 128
#define DEPTH 8

// ---------------- workspace layout (bytes) ----------------
// cen    f64 [512][512]     @ 0          (2 MB) row-major [c][d], rows>=500 zero
// codes  i32 [2048]         @ 2097152
// P      i32 [257]          @ 2105344
// bidx   i32 [2048]         @ 2106400
// routes i32 [2048][128]    @ 2115584    (1 MB) -- region also hosts (dead before routes written):
//   pmax  f64 [8][2048]     @ 2115584    (131072)   written by simsgemm, read by codes2
//   nrm   f64 [2048]        @ 2246656    (16384)    written by norms, read by codes2
//   hist  i32 [8][256]      @ 2115584    (8192)     after codes2: hist/scan
//   choff i32 [8][256]      @ 2123776    (8192)
// qkv    f32 [2048][1536]   @ 3164160    (12 MB)
// Obuf   f32 [2048][512]    @ 15747072   (4 MB)    end 19941376

// ------------------------------------------------------------------
// K1: centroid means, row-major f64. cen[c][d] = mean_v p[c][v][d]; c>=500 -> 0
__global__ __launch_bounds__(256) void centroids_k(const float* __restrict__ p,
                                                   double* __restrict__ cen) {
    int c = blockIdx.x;
    for (int d = threadIdx.x; d < DIM; d += 256) {
        double s = 0.0;
        if (c < NCEN) {
            const float* pc = p + (size_t)c * 5 * DIM;
            s  = (double)pc[0 * DIM + d];
            s += (double)pc[1 * DIM + d];
            s += (double)pc[2 * DIM + d];
            s += (double)pc[3 * DIM + d];
            s += (double)pc[4 * DIM + d];
            s = s / 5.0;
        }
        cen[(size_t)c * DIM + d] = s;
    }
}

// ------------------------------------------------------------------
// K2a: row norms of x in f64. 1 wave per row; 32 blocks x 256 (4 rows/block).
__global__ __launch_bounds__(256) void norms_k(const float* __restrict__ x,
                                               double* __restrict__ nrm) {
    int tid = threadIdx.x;
    int lane = tid & 63;
    int row = blockIdx.x * 4 + (tid >> 6);
    const float* xr = x + (size_t)row * DIM;
    double ss = 0.0;
#pragma unroll
    for (int i = 0; i < 8; ++i) {
        double v = (double)xr[lane + i * 64];
        ss += v * v;
    }
#pragma unroll
    for (int m = 32; m; m >>= 1) ss += __shfl_xor(ss, m);
    if (lane == 0) nrm[row] = sqrt(ss) + 1e-12;
}

// ------------------------------------------------------------------
// K2b: tiled f64 GEMM S = x * cen^T with fused max-over-ctile epilogue.
// grid (8 ctiles, 32 ttiles) x 256 threads. Tile 64 tok x 64 cen, K-chunk 32.
// Thread (tm=tid&15, tn=tid>>4) owns tokens {tm+16i} x cens {tn+16j}.
// pmax[ctile][token] = max over this ctile's VALID cens (c<500) of dot(x,cen).
__global__ __launch_bounds__(256) void simsgemm_k(const float* __restrict__ x,
                                                  const double* __restrict__ cen,
                                                  double* __restrict__ pmax) {
    __shared__ double Xs[32][66];   // [k][token]
    __shared__ double Cs[32][66];   // [k][cen]
    int tid = threadIdx.x;
    int c0 = blockIdx.x * 64;
    int t0 = blockIdx.y * 64;
    int tm = tid & 15, tn = tid >> 4;

    double acc[4][4] = {};
    for (int k0 = 0; k0 < DIM; k0 += 32) {
        // stage X: 64 tok x 32 k (f32 -> f64)
#pragma unroll
        for (int i = 0; i < 2; ++i) {
            int f = i * 256 + tid;
            int r = f >> 3, c4 = (f & 7) * 4;
            float4 va = *(const float4*)(x + (size_t)(t0 + r) * DIM + k0 + c4);
            Xs[c4 + 0][r] = (double)va.x; Xs[c4 + 1][r] = (double)va.y;
            Xs[c4 + 2][r] = (double)va.z; Xs[c4 + 3][r] = (double)va.w;
        }
        // stage C: 64 cen x 32 k (f64)
#pragma unroll
        for (int i = 0; i < 4; ++i) {
            int u = i * 256 + tid;
            int r = u >> 4, kk = (u & 15) * 2;
            double2 vc = *(const double2*)(cen + (size_t)(c0 + r) * DIM + k0 + kk);
            Cs[kk][r] = vc.x; Cs[kk + 1][r] = vc.y;
        }
        __syncthreads();
#pragma unroll 4
        for (int k = 0; k < 32; ++k) {
            double am[4], bn[4];
#pragma unroll
            for (int i = 0; i < 4; ++i) am[i] = Xs[k][tm + 16 * i];
#pragma unroll
            for (int j = 0; j < 4; ++j) bn[j] = Cs[k][tn + 16 * j];
#pragma unroll
            for (int i = 0; i < 4; ++i)
#pragma unroll
                for (int j = 0; j < 4; ++j) acc[i][j] += am[i] * bn[j];
        }
        __syncthreads();
    }

    // fused epilogue: max over this thread's valid cens, then cross-tn reduce
    double (*red)[66] = Xs;   // reuse (all waves past last sync)
#pragma unroll
    for (int i = 0; i < 4; ++i) {
        double m = -1e300;
#pragma unroll
        for (int j = 0; j < 4; ++j) {
            bool valid = (c0 + tn + 16 * j) < NCEN;
            double v = valid ? acc[i][j] : -1e300;
            m = fmax(m, v);
        }
        red[tn][tm + 16 * i] = m;
    }
    __syncthreads();
    if (tid < 64) {
        double m = red[0][tid];
#pragma unroll
        for (int g = 1; g < 16; ++g) m = fmax(m, red[g][tid]);
        pmax[(size_t)blockIdx.x * NTOK + t0 + tid] = m;
    }
}

// ------------------------------------------------------------------
// K2c: final cantor codes. 8 blocks x 256, one thread per token. All f64.
__global__ __launch_bounds__(256) void codes2_k(const double* __restrict__ pmax,
                                                const double* __restrict__ nrm,
                                                const float* __restrict__ gwp,
                                                int* __restrict__ codes) {
    int n = blockIdx.x * 256 + threadIdx.x;
    double m = pmax[n];
#pragma unroll
    for (int g = 1; g < 8; ++g) m = fmax(m, pmax[(size_t)g * NTOK + n]);
    double sims = m / nrm[n];
    double gwv = 1.0 / (1.0 + exp(-(double)gwp[0]));
    const double delta = 1.0 / 2047.0;
    double gd = 1.0 - sims;
    double pos = (n == NTOK - 1) ? 1.0 : (double)n * delta;
    double xc = pos * (1.0 - gwv) + gd * gwv;
    xc = fmin(fmax(xc, 1e-6), 1.0 - 1e-6);
    int code = 0;
#pragma unroll
    for (int l = 0; l < DEPTH; ++l) {
        double s3 = xc * 3.0;
        double dig = floor(s3);
        if (dig == 2.0) code |= 1 << (7 - l);
        xc = s3 - dig;
    }
    codes[n] = code;
}

// ------------------------------------------------------------------
// K3a: per-chunk histogram. 8 blocks x 256.
__global__ __launch_bounds__(256) void hist_k(const int* __restrict__ codes,
                                              int* __restrict__ hist) {
    __shared__ int hl[256];
    int tid = threadIdx.x;
    hl[tid] = 0;
    __syncthreads();
    int c = codes[blockIdx.x * 256 + tid];
    atomicAdd(&hl[c], 1);
    __syncthreads();
    hist[blockIdx.x * 256 + tid] = hl[tid];
}

// K3b: scan -> P[257] and per-chunk offsets. 1 block x 256.
__global__ __launch_bounds__(256) void scan_k(const int* __restrict__ hist,
                                              int* __restrict__ P,
                                              int* __restrict__ chunkoff) {
    __shared__ int sc[256];
    int c = threadIdx.x;
    int h[8];
    int t = 0;
#pragma unroll
    for (int b = 0; b < 8; ++b) { h[b] = hist[b * 256 + c]; t += h[b]; }
    sc[c] = t;
    __syncthreads();
    for (int off = 1; off < 256; off <<= 1) {
        int v = sc[c];
        int add = (c >= off) ? sc[c - off] : 0;
        __syncthreads();
        sc[c] = v + add;
        __syncthreads();
    }
    int incl = sc[c];
    int base = incl - t;
    P[c] = base;
    if (c == 255) P[256] = incl;   // == 2048
    int pre = base;
#pragma unroll
    for (int b = 0; b < 8; ++b) { chunkoff[b * 256 + c] = pre; pre += h[b]; }
}

// K3c: stable scatter. 8 blocks x 256.
__global__ __launch_bounds__(256) void scatter_k(const int* __restrict__ codes,
                                                 const int* __restrict__ chunkoff,
                                                 int* __restrict__ bidx) {
    __shared__ int cl[256];
    int tid = threadIdx.x;
    int b = blockIdx.x;
    int idx = b * 256 + tid;
    int c = codes[idx];
    cl[tid] = c;
    __syncthreads();
    int rank = 0;
    for (int j = 0; j < tid; ++j) rank += (cl[j] == c) ? 1 : 0;
    bidx[chunkoff[b * 256 + c] + rank] = idx;
}

// ------------------------------------------------------------------
// K4: routes, one wave per query. Exact top-k set (order-free).
__global__ __launch_bounds__(256) void routes2_k(const int* __restrict__ codes,
                                                 const int* __restrict__ P,
                                                 const int* __restrict__ bidx,
                                                 int* __restrict__ routes) {
    int tid = threadIdx.x;
    int lane = tid & 63;
    int w = tid >> 6;
    int q = blockIdx.x * 4 + w;
    int ci = codes[q];

    int dstar = -1;
    for (int r = 0; r < 4 && dstar < 0; ++r) {
        int d = r * 64 + lane;
        int loc = ci - d; if (loc < 0) loc = 0;
        int hic = ci + d; if (hic > 255) hic = 255;
        int cum = P[hic + 1] - P[loc];
        unsigned long long m = __ballot(cum >= KWIN);
        if (m) dstar = r * 64 + (int)__builtin_ctzll(m);
    }

    int a = ci - dstar + 1; if (a < 0) a = 0;
    int b = ci + dstar - 1; if (b > 255) b = 255;
    int inner = 0, baseA = 0;
    if (dstar > 0) { baseA = P[a]; inner = P[b + 1] - baseA; }
    int rem = KWIN - inner;
    int* rq = routes + (size_t)q * KWIN;

    for (int t = lane; t < inner; t += 64) rq[t] = bidx[baseA + t];

    int lo = ci - dstar, hi = ci + dstar;
    int loS = 0, loL = 0, hiS = 0, hiL = 0;
    if (lo >= 0) { loS = P[lo]; loL = P[lo + 1] - loS; }
    if (dstar > 0 && hi <= 255) { hiS = P[hi]; hiL = P[hi + 1] - hiS; }

    int minI = rem - hiL; if (minI < 0) minI = 0;
    int maxI = (rem < loL) ? rem : loL;
    int ans = minI;
    int loI = minI, hiI = maxI;
    for (int it = 0; it < 12 && loI <= hiI; ++it) {
        int i = (loI + hiI) >> 1;
        int j = rem - i;
        bool tooMany = (i > 0 && j < hiL && bidx[loS + i - 1] > bidx[hiS + j]);
        bool tooFew  = (j > 0 && i < loL && bidx[hiS + j - 1] > bidx[loS + i]);
        if (tooMany) hiI = i - 1;
        else if (tooFew) loI = i + 1;
        else { ans = i; break; }
    }
    int ilo = ans;
    int jn = rem - ilo;
    for (int t = lane; t < ilo; t += 64) rq[inner + t] = bidx[loS + t];
    for (int t = lane; t < jn; t += 64) rq[inner + ilo + t] = bidx[hiS + t];
}

// ------------------------------------------------------------------
// K5/K7: C[M][Nn] = A[M][512] * B[Nn][512]^T + bias   (f32, 64x64 tile)
__global__ __launch_bounds__(256) void gemm_nt_bias(const float* __restrict__ A,
                                                    const float* __restrict__ Bw,
                                                    const float* __restrict__ bias,
                                                    float* __restrict__ Cc,
                                                    int M, int Nn) {
    __shared__ float As[32][68];
    __shared__ float Bs[32][68];
    int tid = threadIdx.x;
    int n0 = blockIdx.x * 64;
    int m0 = blockIdx.y * 64;
    int tm = tid & 15, tn = tid >> 4;
    float acc[4][4] = {};
    for (int k0 = 0; k0 < 512; k0 += 32) {
#pragma unroll
        for (int i = 0; i < 2; ++i) {
            int f = i * 256 + tid;
            int r = f >> 3, c4 = (f & 7) * 4;
            float4 va = *(const float4*)(A + (size_t)(m0 + r) * 512 + k0 + c4);
            As[c4 + 0][r] = va.x; As[c4 + 1][r] = va.y;
            As[c4 + 2][r] = va.z; As[c4 + 3][r] = va.w;
            float4 vb = *(const float4*)(Bw + (size_t)(n0 + r) * 512 + k0 + c4);
            Bs[c4 + 0][r] = vb.x; Bs[c4 + 1][r] = vb.y;
            Bs[c4 + 2][r] = vb.z; Bs[c4 + 3][r] = vb.w;
        }
        __syncthreads();
#pragma unroll
        for (int k = 0; k < 32; ++k) {
            float4 a4 = *(const float4*)&As[k][tm * 4];
            float4 b4 = *(const float4*)&Bs[k][tn * 4];
            float av[4] = {a4.x, a4.y, a4.z, a4.w};
            float bv[4] = {b4.x, b4.y, b4.z, b4.w};
#pragma unroll
            for (int i = 0; i < 4; ++i)
#pragma unroll
                for (int j = 0; j < 4; ++j) acc[i][j] += av[i] * bv[j];
        }
        __syncthreads();
    }
#pragma unroll
    for (int i = 0; i < 4; ++i) {
        int m = m0 + tm * 4 + i;
        int n = n0 + tn * 4;
        float4 o;
        o.x = acc[i][0] + bias[n + 0];
        o.y = acc[i][1] + bias[n + 1];
        o.z = acc[i][2] + bias[n + 2];
        o.w = acc[i][3] + bias[n + 3];
        *(float4*)(Cc + (size_t)m * Nn + n) = o;
    }
}

// ------------------------------------------------------------------
// K6: sparse attention, row-streaming. 1 block = 1 query (Cantor-sorted order,
// XCD-chunked). 256 threads = 4 waves; wave w owns route slots [w*32,w*32+32).
__global__ __launch_bounds__(256) void attn_v3(const float* __restrict__ qkv,
                                               const int* __restrict__ bidx,
                                               const int* __restrict__ routes,
                                               float* __restrict__ Obuf) {
    __shared__ int rt[KWIN];
    __shared__ float sc[NHEAD][KWIN];
    __shared__ float part[4][DIM];
    int tid = threadIdx.x;
    int lane = tid & 63;
    int w = tid >> 6;

    int b = blockIdx.x;
    int ord = (b & 7) * 256 + (b >> 3);    // XCD-chunked, bijective on [0,2048)
    int q = bidx[ord];

    if (tid < KWIN) rt[tid] = routes[(size_t)q * KWIN + tid];

    const float* qrow = qkv + (size_t)q * 1536 + lane * 8;
    float4 qa = *(const float4*)(qrow);
    float4 qb = *(const float4*)(qrow + 4);
    __syncthreads();

#pragma unroll 4
    for (int i = 0; i < 32; ++i) {
        int kk = w * 32 + i;
        int j = rt[kk];
        const float* kp = qkv + (size_t)j * 1536 + 512 + lane * 8;
        float4 k0 = *(const float4*)(kp);
        float4 k1 = *(const float4*)(kp + 4);
        float s = qa.x * k0.x + qa.y * k0.y + qa.z * k0.z + qa.w * k0.w
                + qb.x * k1.x + qb.y * k1.y + qb.z * k1.z + qb.w * k1.w;
        s += __shfl_xor(s, 1);
        s += __shfl_xor(s, 2);
        s += __shfl_xor(s, 4);
        if ((lane & 7) == 0) sc[lane >> 3][kk] = s * 0.125f;
    }
    __syncthreads();

    {
        int g = tid >> 5, l = tid & 31;
        float v0 = sc[g][l], v1 = sc[g][l + 32], v2 = sc[g][l + 64], v3 = sc[g][l + 96];
        float mx = fmaxf(fmaxf(v0, v1), fmaxf(v2, v3));
        for (int m = 16; m; m >>= 1) mx = fmaxf(mx, __shfl_xor(mx, m, 32));
        float e0 = expf(v0 - mx), e1 = expf(v1 - mx),
              e2 = expf(v2 - mx), e3 = expf(v3 - mx);
        float sum = e0 + e1 + e2 + e3;
        for (int m = 16; m; m >>= 1) sum += __shfl_xor(sum, m, 32);
        float inv = 1.f / sum;
        sc[g][l] = e0 * inv; sc[g][l + 32] = e1 * inv;
        sc[g][l + 64] = e2 * inv; sc[g][l + 96] = e3 * inv;
    }
    __syncthreads();

    float acc[8] = {0.f, 0.f, 0.f, 0.f, 0.f, 0.f, 0.f, 0.f};
    const float* sch = sc[lane >> 3];
#pragma unroll 4
    for (int i = 0; i < 32; ++i) {
        int kk = w * 32 + i;
        int j = rt[kk];
        float wgt = sch[kk];
        const float* vp = qkv + (size_t)j * 1536 + 1024 + lane * 8;
        float4 v0 = *(const float4*)(vp);
        float4 v1 = *(const float4*)(vp + 4);
        acc[0] += wgt * v0.x; acc[1] += wgt * v0.y;
        acc[2] += wgt * v0.z; acc[3] += wgt * v0.w;
        acc[4] += wgt * v1.x; acc[5] += wgt * v1.y;
        acc[6] += wgt * v1.z; acc[7] += wgt * v1.w;
    }
#pragma unroll
    for (int e = 0; e < 8; ++e) part[w][lane * 8 + e] = acc[e];
    __syncthreads();

#pragma unroll
    for (int r = 0; r < 2; ++r) {
        int d = r * 256 + tid;
        float o = part[0][d] + part[1][d] + part[2][d] + part[3][d];
        Obuf[(size_t)q * DIM + d] = o;
    }
}

// ------------------------------------------------------------------
extern "C" void kernel_launch(void* const* d_in, const int* in_sizes, int n_in,
                              void* d_out, int out_size, void* d_ws, size_t ws_size,
                              hipStream_t stream) {
    const float* x      = (const float*)d_in[0];
    const float* penta  = (const float*)d_in[1];
    const float* w_qkv  = (const float*)d_in[2];
    const float* b_qkv  = (const float*)d_in[3];
    const float* w_out  = (const float*)d_in[4];
    const float* b_out  = (const float*)d_in[5];
    const float* gw     = (const float*)d_in[6];
    float* out = (float*)d_out;
    char* ws = (char*)d_ws;

    double* cen   = (double*)(ws + 0);
    int* codes    = (int*)(ws + 2097152);
    int* P        = (int*)(ws + 2105344);
    int* bidx     = (int*)(ws + 2106400);
    int* routes   = (int*)(ws + 2115584);
    // overlapped in routes region (all dead before routes2_k writes routes):
    double* pmax  = (double*)(ws + 2115584);   // [8][2048] f64
    double* nrm   = (double*)(ws + 2246656);   // [2048] f64
    int* hist     = (int*)(ws + 2115584);      // after codes2 done
    int* chunkoff = (int*)(ws + 2123776);
    float* qkv    = (float*)(ws + 3164160);
    float* Obuf   = (float*)(ws + 15747072);

    centroids_k<<<512, 256, 0, stream>>>(penta, cen);
    norms_k<<<512, 256, 0, stream>>>(x, nrm);
    simsgemm_k<<<dim3(8, 32), 256, 0, stream>>>(x, cen, pmax);
    codes2_k<<<8, 256, 0, stream>>>(pmax, nrm, gw, codes);
    hist_k<<<8, 256, 0, stream>>>(codes, hist);
    scan_k<<<1, 256, 0, stream>>>(hist, P, chunkoff);
    scatter_k<<<8, 256, 0, stream>>>(codes, chunkoff, bidx);
    gemm_nt_bias<<<dim3(1536 / 64, 2048 / 64), 256, 0, stream>>>(x, w_qkv, b_qkv, qkv, NTOK, 1536);
    routes2_k<<<512, 256, 0, stream>>>(codes, P, bidx, routes);
    attn_v3<<<NTOK, 256, 0, stream>>>(qkv, bidx, routes, Obuf);
    gemm_nt_bias<<<dim3(512 / 64, 2048 / 64), 256, 0, stream>>>(Obuf, w_out, b_out, out, NTOK, 512);
}